// Round 1
// baseline (665.012 us; speedup 1.0000x reference)
//
#include <hip/hip_runtime.h>

#define DI __device__ __forceinline__

typedef __attribute__((ext_vector_type(8))) short short8v;
typedef __attribute__((ext_vector_type(4))) float f32x4;

static constexpr int B_ = 4, S_ = 2048, D_ = 1024, H_ = 16, HD_ = 64;
static constexpr int M_ = B_ * S_;  // 8192 rows

// f32 -> bf16 round-nearest-even
DI unsigned short f2bf(float f) {
  unsigned u = __builtin_bit_cast(unsigned, f);
  u = (u + 0x7fffu + ((u >> 16) & 1u)) >> 16;
  return (unsigned short)u;
}

// async global->LDS, 16B per lane; LDS dest must be wave-uniform base (HW adds lane*16)
DI void async_copy16(const void* g, void* l) {
  __builtin_amdgcn_global_load_lds((const __attribute__((address_space(1))) void*)g,
                                   (__attribute__((address_space(3))) void*)l, 16, 0, 0);
}

// ---------------- elementwise cast f32 -> bf16 (vectorized) ----------------
__global__ __launch_bounds__(256) void cast_bf16_kernel(const float* __restrict__ in,
                                                        unsigned short* __restrict__ out,
                                                        int n4) {
  int i = blockIdx.x * blockDim.x + threadIdx.x;
  int stride = gridDim.x * blockDim.x;
  for (; i < n4; i += stride) {
    float4 v = reinterpret_cast<const float4*>(in)[i];
    ushort4 o;
    o.x = f2bf(v.x); o.y = f2bf(v.y); o.z = f2bf(v.z); o.w = f2bf(v.w);
    reinterpret_cast<ushort4*>(out)[i] = o;
  }
}

// ---------------- transpose + cast weights: W[K,N] f32 -> Wt[N,K] bf16 ----------------
__global__ __launch_bounds__(256) void transpose_cast_kernel(const float* __restrict__ W,
                                                             unsigned short* __restrict__ Wt,
                                                             int n) {
  __shared__ float t[32][33];
  int bx = blockIdx.x * 32, by = blockIdx.y * 32;
  int x = threadIdx.x, y0 = threadIdx.y;
#pragma unroll
  for (int yy = 0; yy < 32; yy += 8)
    t[y0 + yy][x] = W[(long)(by + y0 + yy) * n + bx + x];
  __syncthreads();
#pragma unroll
  for (int yy = 0; yy < 32; yy += 8)
    Wt[(long)(bx + y0 + yy) * n + by + x] = f2bf(t[x][y0 + yy]);
}

// ---------------- pack mask (0/1 f32) into bit words: bit=1 -> masked out ----------------
__global__ __launch_bounds__(256) void pack_mask_kernel(const float* __restrict__ mask,
                                                        unsigned long long* __restrict__ bits,
                                                        int nwords) {
  int lane = threadIdx.x & 63;
  int wpb = blockDim.x >> 6;
  int w = blockIdx.x * wpb + (threadIdx.x >> 6);
  int stride = gridDim.x * wpb;
  for (; w < nwords; w += stride) {
    float v = mask[(long)w * 64 + lane];
    unsigned long long b = __ballot(v > 0.5f);
    if (lane == 0) bits[w] = b;
  }
}

// ---------------- GEMM: C[M,N] = A[M,K] * Bt[N,K]^T + bias, bf16 MFMA ----------------
// MODE 0: bf16 out [M,N], val=(acc+bias)*scale
// MODE 1: bf16 out as per-head transposed V: Vt[(b*16+h)*64+d][s], S=2048
// MODE 2: f32 out [M,N]
template <int MODE>
__global__ __launch_bounds__(256) void gemm_bt_kernel(const unsigned short* __restrict__ A,
                                                      const unsigned short* __restrict__ Bt,
                                                      const float* __restrict__ bias,
                                                      void* __restrict__ out,
                                                      int Mdim, int Ndim, int Kdim, float scale) {
  __shared__ unsigned short As[128 * 32];
  __shared__ unsigned short Bs[128 * 32];
  const int tid = threadIdx.x;
  const int lane = tid & 63;
  const int w = tid >> 6;
  const int g = lane >> 4;
  const int l15 = lane & 15;
  const int bm = blockIdx.x * 128;
  const int bn = blockIdx.y * 128;
  const int wr = w >> 1, wc = w & 1;

  f32x4 zero = {0.f, 0.f, 0.f, 0.f};
  f32x4 acc[4][4];
#pragma unroll
  for (int i = 0; i < 4; ++i)
#pragma unroll
    for (int j = 0; j < 4; ++j) acc[i][j] = zero;

  const int srow = lane >> 2;        // 0..15 within 16-row chunk
  const int scol = (lane & 3) * 8;   // bf16 col offset, 8 elems = 16B

  for (int k0 = 0; k0 < Kdim; k0 += 32) {
#pragma unroll
    for (int i = 0; i < 2; ++i) {
      int q = w * 2 + i;             // 1KB chunk index, rows [q*16, q*16+16)
      int row = q * 16 + srow;
      async_copy16(&A[(long)(bm + row) * Kdim + k0 + scol], &As[q * 512]);
      async_copy16(&Bt[(long)(bn + row) * Kdim + k0 + scol], &Bs[q * 512]);
    }
    __syncthreads();
    short8v a[4], b[4];
#pragma unroll
    for (int i = 0; i < 4; ++i)
      a[i] = *reinterpret_cast<const short8v*>(&As[(wr * 64 + i * 16 + l15) * 32 + g * 8]);
#pragma unroll
    for (int j = 0; j < 4; ++j)
      b[j] = *reinterpret_cast<const short8v*>(&Bs[(wc * 64 + j * 16 + l15) * 32 + g * 8]);
#pragma unroll
    for (int i = 0; i < 4; ++i)
#pragma unroll
      for (int j = 0; j < 4; ++j)
        acc[i][j] = __builtin_amdgcn_mfma_f32_16x16x32_bf16(a[i], b[j], acc[i][j], 0, 0, 0);
    __syncthreads();
  }

#pragma unroll
  for (int jj = 0; jj < 4; ++jj) {
    int n = bn + wc * 64 + jj * 16 + l15;
    float bs = bias[n];
#pragma unroll
    for (int i = 0; i < 4; ++i) {
      int m0 = bm + wr * 64 + i * 16 + g * 4;  // rows m0..m0+3 (reg r)
      if (MODE == 0) {
        unsigned short* o = (unsigned short*)out;
#pragma unroll
        for (int r = 0; r < 4; ++r)
          o[(long)(m0 + r) * Ndim + n] = f2bf((acc[i][jj][r] + bs) * scale);
      } else if (MODE == 1) {
        int b2 = m0 >> 11, s0 = m0 & 2047;
        int h2 = n >> 6, d2 = n & 63;
        unsigned short* o = (unsigned short*)out;
        ushort4 v;
        v.x = f2bf(acc[i][jj][0] + bs);
        v.y = f2bf(acc[i][jj][1] + bs);
        v.z = f2bf(acc[i][jj][2] + bs);
        v.w = f2bf(acc[i][jj][3] + bs);
        *reinterpret_cast<ushort4*>(&o[((long)((b2 * 16 + h2) * 64 + d2) << 11) + s0]) = v;
      } else {
        float* o = (float*)out;
#pragma unroll
        for (int r = 0; r < 4; ++r)
          o[(long)(m0 + r) * Ndim + n] = acc[i][jj][r] + bs;
      }
    }
  }
}

// ---------------- fused flash attention ----------------
// grid (S/64, B*H), 4 waves; wave w owns q rows qt*64+w*16..+15.
// Transposed logits Lt = mfma(K_frag, Q_frag): acc col = q = lane&15, row = key.
__global__ __launch_bounds__(256) void attn_kernel(const unsigned short* __restrict__ Q,   // [B,S,D] pre-scaled 1/8
                                                   const unsigned short* __restrict__ Kb,  // [B,S,D]
                                                   const unsigned short* __restrict__ Vt,  // [B*H,64,S]
                                                   const unsigned long long* __restrict__ mbits, // [B,S,S/64]
                                                   unsigned short* __restrict__ attn) {    // [B,S,D]
  __shared__ unsigned short plds[4][16][72];  // per-wave P^T bounce tile, pad=8
  const int lane = threadIdx.x & 63;
  const int w = threadIdx.x >> 6;
  const int g = lane >> 4;
  const int l15 = lane & 15;
  const int qt = blockIdx.x;
  const int bh = blockIdx.y;
  const int b = bh >> 4, h = bh & 15;
  const int q = qt * 64 + w * 16 + l15;

  // Q fragment doubles as MFMA B-operand: col n=q=lane&15, k=d=g*8+j (+32)
  const unsigned short* qp = Q + ((long)b * S_ + q) * D_ + h * HD_ + g * 8;
  short8v qf0 = *reinterpret_cast<const short8v*>(qp);
  short8v qf1 = *reinterpret_cast<const short8v*>(qp + 32);

  f32x4 zero = {0.f, 0.f, 0.f, 0.f};
  f32x4 oacc[4] = {zero, zero, zero, zero};  // O^T: rows d (4x16), col q
  float m_run = -1e30f, l_run = 0.f;

  const unsigned short* kbase = Kb + (long)b * S_ * D_ + h * HD_ + g * 8;
  const unsigned short* vbase = Vt + (long)bh * HD_ * S_ + g * 8;
  const unsigned long long* mrow = mbits + ((long)b * S_ + q) * (S_ / 64);

  for (int kt = 0; kt < S_; kt += 64) {
    // QK^T (transposed): 4 key sub-tiles of 16
    f32x4 lt[4];
#pragma unroll
    for (int g2 = 0; g2 < 4; ++g2) {
      const unsigned short* kp = kbase + (long)(kt + g2 * 16 + l15) * D_;
      short8v k0 = *reinterpret_cast<const short8v*>(kp);
      short8v k1 = *reinterpret_cast<const short8v*>(kp + 32);
      f32x4 c = zero;
      c = __builtin_amdgcn_mfma_f32_16x16x32_bf16(k0, qf0, c, 0, 0, 0);
      c = __builtin_amdgcn_mfma_f32_16x16x32_bf16(k1, qf1, c, 0, 0, 0);
      lt[g2] = c;
    }
    // mask: one u64 covers keys [kt,kt+64) for this lane's q
    unsigned long long mw = mrow[kt >> 6];
    float tmax = -1e30f;
#pragma unroll
    for (int g2 = 0; g2 < 4; ++g2)
#pragma unroll
      for (int r = 0; r < 4; ++r) {
        int krel = g2 * 16 + g * 4 + r;  // Lt row = key = g2*16 + g*4 + r
        float v = ((mw >> krel) & 1ull) ? -1e30f : lt[g2][r];
        lt[g2][r] = v;
        tmax = fmaxf(tmax, v);
      }
    tmax = fmaxf(tmax, __shfl_xor(tmax, 16));
    tmax = fmaxf(tmax, __shfl_xor(tmax, 32));
    float m_new = fmaxf(m_run, tmax);
    float alpha = __expf(m_run - m_new);
    float tsum = 0.f;
#pragma unroll
    for (int g2 = 0; g2 < 4; ++g2) {
      float p0 = __expf(lt[g2][0] - m_new);
      float p1 = __expf(lt[g2][1] - m_new);
      float p2 = __expf(lt[g2][2] - m_new);
      float p3 = __expf(lt[g2][3] - m_new);
      tsum += p0 + p1 + p2 + p3;
      ushort4 pk;
      pk.x = f2bf(p0); pk.y = f2bf(p1); pk.z = f2bf(p2); pk.w = f2bf(p3);
      // P^T stored q-major: row=q(l15), cols = 4 consecutive keys
      *reinterpret_cast<ushort4*>(&plds[w][l15][g2 * 16 + g * 4]) = pk;
    }
    tsum += __shfl_xor(tsum, 16);
    tsum += __shfl_xor(tsum, 32);
    l_run = l_run * alpha + tsum;
    m_run = m_new;
#pragma unroll
    for (int d = 0; d < 4; ++d) oacc[d] *= alpha;
    // PV: O^T += V^T * P^T  (same-wave LDS exchange, no barrier needed)
#pragma unroll
    for (int ks = 0; ks < 2; ++ks) {
      short8v pf = *reinterpret_cast<const short8v*>(&plds[w][l15][ks * 32 + g * 8]);
      const unsigned short* vp = vbase + kt + ks * 32;
#pragma unroll
      for (int d = 0; d < 4; ++d) {
        short8v vf = *reinterpret_cast<const short8v*>(&vp[(long)(d * 16 + l15) * S_]);
        oacc[d] = __builtin_amdgcn_mfma_f32_16x16x32_bf16(vf, pf, oacc[d], 0, 0, 0);
      }
    }
  }
  float inv = 1.f / l_run;
#pragma unroll
  for (int d = 0; d < 4; ++d) {
    ushort4 o;
    o.x = f2bf(oacc[d][0] * inv);
    o.y = f2bf(oacc[d][1] * inv);
    o.z = f2bf(oacc[d][2] * inv);
    o.w = f2bf(oacc[d][3] * inv);
    *reinterpret_cast<ushort4*>(&attn[((long)b * S_ + q) * D_ + h * HD_ + d * 16 + g * 4]) = o;
  }
}

// ---------------- launch ----------------
extern "C" void kernel_launch(void* const* d_in, const int* in_sizes, int n_in,
                              void* d_out, int out_size, void* d_ws, size_t ws_size,
                              hipStream_t stream) {
  const float* query = (const float*)d_in[0];
  const float* key   = (const float*)d_in[1];
  const float* value = (const float*)d_in[2];
  const float* mask  = (const float*)d_in[3];
  const float* Wq = (const float*)d_in[4];
  const float* bq = (const float*)d_in[5];
  const float* Wk = (const float*)d_in[6];
  const float* bk = (const float*)d_in[7];
  const float* Wv = (const float*)d_in[8];
  const float* bv = (const float*)d_in[9];
  const float* Wo = (const float*)d_in[10];
  const float* bo = (const float*)d_in[11];

  char* ws = (char*)d_ws;
  // layout (bytes): XQ 0..16M, XK 16..32M, XV 32..48M, weights 48..56M,
  // QB 56..72M, KB 72..88M, VT 88..104M. attn reuses XQ, mask bits reuse XK.
  unsigned short* XQ  = (unsigned short*)(ws);
  unsigned short* XK  = (unsigned short*)(ws + (16ull << 20));
  unsigned short* XV  = (unsigned short*)(ws + (32ull << 20));
  unsigned short* WQT = (unsigned short*)(ws + (48ull << 20));
  unsigned short* WKT = (unsigned short*)(ws + (50ull << 20));
  unsigned short* WVT = (unsigned short*)(ws + (52ull << 20));
  unsigned short* WOT = (unsigned short*)(ws + (54ull << 20));
  unsigned short* QB  = (unsigned short*)(ws + (56ull << 20));
  unsigned short* KB  = (unsigned short*)(ws + (72ull << 20));
  unsigned short* VT  = (unsigned short*)(ws + (88ull << 20));
  unsigned long long* MBITS = (unsigned long long*)(ws + (16ull << 20));
  unsigned short* ATTN = XQ;

  const int n4 = M_ * D_ / 4;
  cast_bf16_kernel<<<2048, 256, 0, stream>>>(query, XQ, n4);
  cast_bf16_kernel<<<2048, 256, 0, stream>>>(key,   XK, n4);
  cast_bf16_kernel<<<2048, 256, 0, stream>>>(value, XV, n4);

  dim3 tg(D_ / 32, D_ / 32), tb(32, 8);
  transpose_cast_kernel<<<tg, tb, 0, stream>>>(Wq, WQT, D_);
  transpose_cast_kernel<<<tg, tb, 0, stream>>>(Wk, WKT, D_);
  transpose_cast_kernel<<<tg, tb, 0, stream>>>(Wv, WVT, D_);
  transpose_cast_kernel<<<tg, tb, 0, stream>>>(Wo, WOT, D_);

  dim3 gg(M_ / 128, D_ / 128);
  gemm_bt_kernel<0><<<gg, 256, 0, stream>>>(XQ, WQT, bq, QB, M_, D_, D_, 0.125f);  // 1/sqrt(HD) folded
  gemm_bt_kernel<0><<<gg, 256, 0, stream>>>(XK, WKT, bk, KB, M_, D_, D_, 1.f);
  gemm_bt_kernel<1><<<gg, 256, 0, stream>>>(XV, WVT, bv, VT, M_, D_, D_, 1.f);

  pack_mask_kernel<<<2048, 256, 0, stream>>>(mask, MBITS, B_ * S_ * S_ / 64);

  dim3 ag(S_ / 64, B_ * H_);
  attn_kernel<<<ag, 256, 0, stream>>>(QB, KB, VT, MBITS, ATTN);

  gemm_bt_kernel<2><<<gg, 256, 0, stream>>>(ATTN, WOT, bo, d_out, M_, D_, D_, 1.f);
}

// Round 2
// 338.662 us; speedup vs baseline: 1.9636x; 1.9636x over previous
//
#include <hip/hip_runtime.h>

#define DI __device__ __forceinline__

typedef __attribute__((ext_vector_type(8))) short short8v;
typedef __attribute__((ext_vector_type(4))) float f32x4;

static constexpr int B_ = 4, S_ = 2048, D_ = 1024, H_ = 16, HD_ = 64;
static constexpr int M_ = B_ * S_;  // 8192 rows

// f32 -> bf16 round-nearest-even
DI unsigned short f2bf(float f) {
  unsigned u = __builtin_bit_cast(unsigned, f);
  u = (u + 0x7fffu + ((u >> 16) & 1u)) >> 16;
  return (unsigned short)u;
}

// async global->LDS, 16B per lane; LDS dest must be wave-uniform base (HW adds lane*16)
DI void async_copy16(const void* g, void* l) {
  __builtin_amdgcn_global_load_lds((const __attribute__((address_space(1))) void*)g,
                                   (__attribute__((address_space(3))) void*)l, 16, 0, 0);
}

// ---------------- elementwise cast f32 -> bf16 (vectorized) ----------------
__global__ __launch_bounds__(256) void cast_bf16_kernel(const float* __restrict__ in,
                                                        unsigned short* __restrict__ out,
                                                        int n4) {
  int i = blockIdx.x * blockDim.x + threadIdx.x;
  int stride = gridDim.x * blockDim.x;
  for (; i < n4; i += stride) {
    float4 v = reinterpret_cast<const float4*>(in)[i];
    ushort4 o;
    o.x = f2bf(v.x); o.y = f2bf(v.y); o.z = f2bf(v.z); o.w = f2bf(v.w);
    reinterpret_cast<ushort4*>(out)[i] = o;
  }
}

// ---------------- transpose + cast weights: W[K,N] f32 -> Wt[N,K] bf16 ----------------
__global__ __launch_bounds__(256) void transpose_cast_kernel(const float* __restrict__ W,
                                                             unsigned short* __restrict__ Wt,
                                                             int n) {
  __shared__ float t[32][33];
  int bx = blockIdx.x * 32, by = blockIdx.y * 32;
  int x = threadIdx.x, y0 = threadIdx.y;
#pragma unroll
  for (int yy = 0; yy < 32; yy += 8)
    t[y0 + yy][x] = W[(long)(by + y0 + yy) * n + bx + x];
  __syncthreads();
#pragma unroll
  for (int yy = 0; yy < 32; yy += 8)
    Wt[(long)(bx + y0 + yy) * n + by + x] = f2bf(t[x][y0 + yy]);
}

// ---------------- pack mask (0/1 f32) into bit words: bit=1 -> masked out ----------------
__global__ __launch_bounds__(256) void pack_mask_kernel(const float* __restrict__ mask,
                                                        unsigned long long* __restrict__ bits,
                                                        int nwords) {
  int lane = threadIdx.x & 63;
  int wpb = blockDim.x >> 6;
  int w = blockIdx.x * wpb + (threadIdx.x >> 6);
  int stride = gridDim.x * wpb;
  for (; w < nwords; w += stride) {
    float v = mask[(long)w * 64 + lane];
    unsigned long long b = __ballot(v > 0.5f);
    if (lane == 0) bits[w] = b;
  }
}

// ---------------- GEMM: C[M,N] = A[M,K] * Bt[N,K]^T + bias, bf16 MFMA ----------------
// MODE 0: bf16 out [M,N], val=(acc+bias)*scale
// MODE 1: bf16 out as per-head transposed V: Vt[(b*16+h)*64+d][s], S=2048
// MODE 2: f32 out [M,N]
template <int MODE>
__global__ __launch_bounds__(256) void gemm_bt_kernel(const unsigned short* __restrict__ A,
                                                      const unsigned short* __restrict__ Bt,
                                                      const float* __restrict__ bias,
                                                      void* __restrict__ out,
                                                      int Mdim, int Ndim, int Kdim, float scale) {
  __shared__ unsigned short As[128 * 32];
  __shared__ unsigned short Bs[128 * 32];
  const int tid = threadIdx.x;
  const int lane = tid & 63;
  const int w = tid >> 6;
  const int g = lane >> 4;
  const int l15 = lane & 15;
  const int bm = blockIdx.x * 128;
  const int bn = blockIdx.y * 128;
  const int wr = w >> 1, wc = w & 1;

  f32x4 zero = {0.f, 0.f, 0.f, 0.f};
  f32x4 acc[4][4];
#pragma unroll
  for (int i = 0; i < 4; ++i)
#pragma unroll
    for (int j = 0; j < 4; ++j) acc[i][j] = zero;

  const int srow = lane >> 2;        // 0..15 within 16-row chunk
  const int scol = (lane & 3) * 8;   // bf16 col offset, 8 elems = 16B

  for (int k0 = 0; k0 < Kdim; k0 += 32) {
#pragma unroll
    for (int i = 0; i < 2; ++i) {
      int q = w * 2 + i;             // 1KB chunk index, rows [q*16, q*16+16)
      int row = q * 16 + srow;
      async_copy16(&A[(long)(bm + row) * Kdim + k0 + scol], &As[q * 512]);
      async_copy16(&Bt[(long)(bn + row) * Kdim + k0 + scol], &Bs[q * 512]);
    }
    __syncthreads();
    short8v a[4], b[4];
#pragma unroll
    for (int i = 0; i < 4; ++i)
      a[i] = *reinterpret_cast<const short8v*>(&As[(wr * 64 + i * 16 + l15) * 32 + g * 8]);
#pragma unroll
    for (int j = 0; j < 4; ++j)
      b[j] = *reinterpret_cast<const short8v*>(&Bs[(wc * 64 + j * 16 + l15) * 32 + g * 8]);
#pragma unroll
    for (int i = 0; i < 4; ++i)
#pragma unroll
      for (int j = 0; j < 4; ++j)
        acc[i][j] = __builtin_amdgcn_mfma_f32_16x16x32_bf16(a[i], b[j], acc[i][j], 0, 0, 0);
    __syncthreads();
  }

#pragma unroll
  for (int jj = 0; jj < 4; ++jj) {
    int n = bn + wc * 64 + jj * 16 + l15;
    float bs = bias[n];
#pragma unroll
    for (int i = 0; i < 4; ++i) {
      int m0 = bm + wr * 64 + i * 16 + g * 4;  // rows m0..m0+3 (reg r)
      if (MODE == 0) {
        unsigned short* o = (unsigned short*)out;
#pragma unroll
        for (int r = 0; r < 4; ++r)
          o[(long)(m0 + r) * Ndim + n] = f2bf((acc[i][jj][r] + bs) * scale);
      } else if (MODE == 1) {
        int b2 = m0 >> 11, s0 = m0 & 2047;
        int h2 = n >> 6, d2 = n & 63;
        unsigned short* o = (unsigned short*)out;
        ushort4 v;
        v.x = f2bf(acc[i][jj][0] + bs);
        v.y = f2bf(acc[i][jj][1] + bs);
        v.z = f2bf(acc[i][jj][2] + bs);
        v.w = f2bf(acc[i][jj][3] + bs);
        *reinterpret_cast<ushort4*>(&o[((long)((b2 * 16 + h2) * 64 + d2) << 11) + s0]) = v;
      } else {
        float* o = (float*)out;
#pragma unroll
        for (int r = 0; r < 4; ++r)
          o[(long)(m0 + r) * Ndim + n] = acc[i][jj][r] + bs;
      }
    }
  }
}

// ---------------- fused flash attention (v2: LDS-shared K/V tiles) ----------------
// grid (S/128, B*H), 4 waves; wave w owns q rows qt*128 + w*32 .. +31 (2 q-fragments).
// K tile [64 keys][64 d] and V^T tile [64 d][64 keys] staged in LDS via global_load_lds,
// XOR-swizzled (chunk ^= row&7) to break the 128B-row-stride bank conflict.
// Transposed logits Lt = mfma(K_frag, Q_frag): acc col = q = lane&15, row = key.
__global__ __launch_bounds__(256, 3) void attn_kernel(const unsigned short* __restrict__ Q,   // [B,S,D] pre-scaled 1/8
                                                      const unsigned short* __restrict__ Kb,  // [B,S,D]
                                                      const unsigned short* __restrict__ Vt,  // [B*H,64,S]
                                                      const unsigned long long* __restrict__ mbits, // [B,S,S/64]
                                                      unsigned short* __restrict__ attn) {    // [B,S,D]
  __shared__ unsigned short Ks[64 * 64];       // swizzled, rows = key
  __shared__ unsigned short Vs[64 * 64];       // swizzled, rows = d
  __shared__ unsigned short plds[4][2][16][72];  // per-wave/qf P^T bounce tile, pad=8
  const int lane = threadIdx.x & 63;
  const int w = threadIdx.x >> 6;
  const int g = lane >> 4;
  const int l15 = lane & 15;
  const int qt = blockIdx.x;
  const int bh = blockIdx.y;
  const int b = bh >> 4, h = bh & 15;
  const int q0 = qt * 128 + w * 32 + l15;  // qf=0 row; qf=1 row = q0+16

  // Q fragments double as MFMA B-operand: col n=q=lane&15, k=d=g*8+j (+32)
  const unsigned short* qp = Q + ((long)b * S_ + q0) * D_ + h * HD_ + g * 8;
  short8v qfr[2][2];
  qfr[0][0] = *reinterpret_cast<const short8v*>(qp);
  qfr[0][1] = *reinterpret_cast<const short8v*>(qp + 32);
  qfr[1][0] = *reinterpret_cast<const short8v*>(qp + 16 * D_);
  qfr[1][1] = *reinterpret_cast<const short8v*>(qp + 16 * D_ + 32);

  // staging: lane covers LDS (row = blk8*8 + lane>>3, chunk = lane&7); source chunk
  // is inverse-swizzled so that the linear LDS write lands swizzled (rule: both sides).
  const int srow = lane >> 3;
  const int schunk = ((lane & 7) ^ (lane >> 3)) * 8;  // in elements
  const unsigned short* kstage = Kb + (long)b * S_ * D_ + h * HD_;
  const unsigned short* vstage = Vt + (long)bh * HD_ * S_;

  f32x4 zero = {0.f, 0.f, 0.f, 0.f};
  f32x4 oacc[2][4];
#pragma unroll
  for (int qf = 0; qf < 2; ++qf)
#pragma unroll
    for (int d = 0; d < 4; ++d) oacc[qf][d] = zero;
  float m_run[2] = {-1e30f, -1e30f}, l_run[2] = {0.f, 0.f};

  const unsigned long long* mrow[2];
  mrow[0] = mbits + ((long)b * S_ + q0) * (S_ / 64);
  mrow[1] = mrow[0] + 16 * (S_ / 64);
  const int swz = l15 & 7;

  for (int kt = 0; kt < S_; kt += 64) {
    // ---- stage K/V tile (each wave issues 2+2 wave-loads of 1KB) ----
#pragma unroll
    for (int i = 0; i < 2; ++i) {
      int blk8 = w * 2 + i;
      async_copy16(&kstage[(long)(kt + blk8 * 8 + srow) * D_ + schunk], &Ks[blk8 * 512]);
      async_copy16(&vstage[(long)(blk8 * 8 + srow) * S_ + kt + schunk], &Vs[blk8 * 512]);
    }
    __syncthreads();

    // ---- QK^T (transposed), K frags shared across both q-fragments ----
    f32x4 lt[2][4];
#pragma unroll
    for (int g2 = 0; g2 < 4; ++g2) {
      const unsigned short* kr = &Ks[(g2 * 16 + l15) * 64];
      short8v kf0 = *reinterpret_cast<const short8v*>(&kr[(g ^ swz) * 8]);
      short8v kf1 = *reinterpret_cast<const short8v*>(&kr[((g + 4) ^ swz) * 8]);
#pragma unroll
      for (int qf = 0; qf < 2; ++qf) {
        f32x4 c = zero;
        c = __builtin_amdgcn_mfma_f32_16x16x32_bf16(kf0, qfr[qf][0], c, 0, 0, 0);
        c = __builtin_amdgcn_mfma_f32_16x16x32_bf16(kf1, qfr[qf][1], c, 0, 0, 0);
        lt[qf][g2] = c;
      }
    }

    // ---- online softmax per q-fragment + P^T repack through per-wave LDS ----
    short8v pf[2][2];
#pragma unroll
    for (int qf = 0; qf < 2; ++qf) {
      unsigned long long mw = mrow[qf][kt >> 6];
      float tmax = -1e30f;
#pragma unroll
      for (int g2 = 0; g2 < 4; ++g2)
#pragma unroll
        for (int r = 0; r < 4; ++r) {
          int krel = g2 * 16 + g * 4 + r;  // Lt row = key
          float v = ((mw >> krel) & 1ull) ? -1e30f : lt[qf][g2][r];
          lt[qf][g2][r] = v;
          tmax = fmaxf(tmax, v);
        }
      tmax = fmaxf(tmax, __shfl_xor(tmax, 16));
      tmax = fmaxf(tmax, __shfl_xor(tmax, 32));
      float m_new = fmaxf(m_run[qf], tmax);
      float alpha = __expf(m_run[qf] - m_new);
      float tsum = 0.f;
#pragma unroll
      for (int g2 = 0; g2 < 4; ++g2) {
        float p0 = __expf(lt[qf][g2][0] - m_new);
        float p1 = __expf(lt[qf][g2][1] - m_new);
        float p2 = __expf(lt[qf][g2][2] - m_new);
        float p3 = __expf(lt[qf][g2][3] - m_new);
        tsum += p0 + p1 + p2 + p3;
        ushort4 pk;
        pk.x = f2bf(p0); pk.y = f2bf(p1); pk.z = f2bf(p2); pk.w = f2bf(p3);
        *reinterpret_cast<ushort4*>(&plds[w][qf][l15][g2 * 16 + g * 4]) = pk;
      }
      tsum += __shfl_xor(tsum, 16);
      tsum += __shfl_xor(tsum, 32);
      l_run[qf] = l_run[qf] * alpha + tsum;
      m_run[qf] = m_new;
#pragma unroll
      for (int d = 0; d < 4; ++d) oacc[qf][d] *= alpha;
      // P^T fragment: col=q=l15, k=key=g*8+j (+32); same-wave exchange, no barrier
      pf[qf][0] = *reinterpret_cast<const short8v*>(&plds[w][qf][l15][g * 8]);
      pf[qf][1] = *reinterpret_cast<const short8v*>(&plds[w][qf][l15][32 + g * 8]);
    }

    // ---- PV: O^T += V^T * P^T, V frags shared across both q-fragments ----
#pragma unroll
    for (int d0 = 0; d0 < 4; ++d0) {
      const unsigned short* vr = &Vs[(d0 * 16 + l15) * 64];
      short8v vf0 = *reinterpret_cast<const short8v*>(&vr[(g ^ swz) * 8]);
      short8v vf1 = *reinterpret_cast<const short8v*>(&vr[((g + 4) ^ swz) * 8]);
#pragma unroll
      for (int qf = 0; qf < 2; ++qf) {
        oacc[qf][d0] = __builtin_amdgcn_mfma_f32_16x16x32_bf16(vf0, pf[qf][0], oacc[qf][d0], 0, 0, 0);
        oacc[qf][d0] = __builtin_amdgcn_mfma_f32_16x16x32_bf16(vf1, pf[qf][1], oacc[qf][d0], 0, 0, 0);
      }
    }
    __syncthreads();
  }

#pragma unroll
  for (int qf = 0; qf < 2; ++qf) {
    float inv = 1.f / l_run[qf];
    int q = q0 + qf * 16;
#pragma unroll
    for (int d0 = 0; d0 < 4; ++d0) {
      ushort4 o;
      o.x = f2bf(oacc[qf][d0][0] * inv);
      o.y = f2bf(oacc[qf][d0][1] * inv);
      o.z = f2bf(oacc[qf][d0][2] * inv);
      o.w = f2bf(oacc[qf][d0][3] * inv);
      *reinterpret_cast<ushort4*>(&attn[((long)b * S_ + q) * D_ + h * HD_ + d0 * 16 + g * 4]) = o;
    }
  }
}

// ---------------- launch ----------------
extern "C" void kernel_launch(void* const* d_in, const int* in_sizes, int n_in,
                              void* d_out, int out_size, void* d_ws, size_t ws_size,
                              hipStream_t stream) {
  const float* query = (const float*)d_in[0];
  const float* key   = (const float*)d_in[1];
  const float* value = (const float*)d_in[2];
  const float* mask  = (const float*)d_in[3];
  const float* Wq = (const float*)d_in[4];
  const float* bq = (const float*)d_in[5];
  const float* Wk = (const float*)d_in[6];
  const float* bk = (const float*)d_in[7];
  const float* Wv = (const float*)d_in[8];
  const float* bv = (const float*)d_in[9];
  const float* Wo = (const float*)d_in[10];
  const float* bo = (const float*)d_in[11];

  char* ws = (char*)d_ws;
  // layout (bytes): XQ 0..16M, XK 16..32M, XV 32..48M, weights 48..56M,
  // QB 56..72M, KB 72..88M, VT 88..104M. attn reuses XQ, mask bits reuse XK.
  unsigned short* XQ  = (unsigned short*)(ws);
  unsigned short* XK  = (unsigned short*)(ws + (16ull << 20));
  unsigned short* XV  = (unsigned short*)(ws + (32ull << 20));
  unsigned short* WQT = (unsigned short*)(ws + (48ull << 20));
  unsigned short* WKT = (unsigned short*)(ws + (50ull << 20));
  unsigned short* WVT = (unsigned short*)(ws + (52ull << 20));
  unsigned short* WOT = (unsigned short*)(ws + (54ull << 20));
  unsigned short* QB  = (unsigned short*)(ws + (56ull << 20));
  unsigned short* KB  = (unsigned short*)(ws + (72ull << 20));
  unsigned short* VT  = (unsigned short*)(ws + (88ull << 20));
  unsigned long long* MBITS = (unsigned long long*)(ws + (16ull << 20));
  unsigned short* ATTN = XQ;

  const int n4 = M_ * D_ / 4;
  cast_bf16_kernel<<<2048, 256, 0, stream>>>(query, XQ, n4);
  cast_bf16_kernel<<<2048, 256, 0, stream>>>(key,   XK, n4);
  cast_bf16_kernel<<<2048, 256, 0, stream>>>(value, XV, n4);

  dim3 tg(D_ / 32, D_ / 32), tb(32, 8);
  transpose_cast_kernel<<<tg, tb, 0, stream>>>(Wq, WQT, D_);
  transpose_cast_kernel<<<tg, tb, 0, stream>>>(Wk, WKT, D_);
  transpose_cast_kernel<<<tg, tb, 0, stream>>>(Wv, WVT, D_);
  transpose_cast_kernel<<<tg, tb, 0, stream>>>(Wo, WOT, D_);

  dim3 gg(M_ / 128, D_ / 128);
  gemm_bt_kernel<0><<<gg, 256, 0, stream>>>(XQ, WQT, bq, QB, M_, D_, D_, 0.125f);  // 1/sqrt(HD) folded
  gemm_bt_kernel<0><<<gg, 256, 0, stream>>>(XK, WKT, bk, KB, M_, D_, D_, 1.f);
  gemm_bt_kernel<1><<<gg, 256, 0, stream>>>(XV, WVT, bv, VT, M_, D_, D_, 1.f);

  pack_mask_kernel<<<2048, 256, 0, stream>>>(mask, MBITS, B_ * S_ * S_ / 64);

  dim3 ag(S_ / 128, B_ * H_);
  attn_kernel<<<ag, 256, 0, stream>>>(QB, KB, VT, MBITS, ATTN);

  gemm_bt_kernel<2><<<gg, 256, 0, stream>>>(ATTN, WOT, bo, d_out, M_, D_, D_, 1.f);
}

// Round 3
// 311.185 us; speedup vs baseline: 2.1370x; 1.0883x over previous
//
#include <hip/hip_runtime.h>

#define DI __device__ __forceinline__

typedef __attribute__((ext_vector_type(8))) short short8v;
typedef __attribute__((ext_vector_type(4))) float f32x4;

static constexpr int B_ = 4, S_ = 2048, D_ = 1024, H_ = 16, HD_ = 64;
static constexpr int M_ = B_ * S_;  // 8192 rows

// f32 -> bf16 round-nearest-even
DI unsigned short f2bf(float f) {
  unsigned u = __builtin_bit_cast(unsigned, f);
  u = (u + 0x7fffu + ((u >> 16) & 1u)) >> 16;
  return (unsigned short)u;
}

DI unsigned cvt_pk_bf16(float lo, float hi) {
  unsigned r;
  asm("v_cvt_pk_bf16_f32 %0, %1, %2" : "=v"(r) : "v"(lo), "v"(hi));
  return r;
}

// async global->LDS, 16B per lane; LDS dest must be wave-uniform base (HW adds lane*16)
DI void async_copy16(const void* g, void* l) {
  __builtin_amdgcn_global_load_lds((const __attribute__((address_space(1))) void*)g,
                                   (__attribute__((address_space(3))) void*)l, 16, 0, 0);
}

// ---------------- elementwise cast f32 -> bf16 (vectorized) ----------------
__global__ __launch_bounds__(256) void cast_bf16_kernel(const float* __restrict__ in,
                                                        unsigned short* __restrict__ out,
                                                        int n4) {
  int i = blockIdx.x * blockDim.x + threadIdx.x;
  int stride = gridDim.x * blockDim.x;
  for (; i < n4; i += stride) {
    float4 v = reinterpret_cast<const float4*>(in)[i];
    ushort4 o;
    o.x = f2bf(v.x); o.y = f2bf(v.y); o.z = f2bf(v.z); o.w = f2bf(v.w);
    reinterpret_cast<ushort4*>(out)[i] = o;
  }
}

// ---------------- transpose + cast weights: W[K,N] f32 -> Wt[N,K] bf16 ----------------
__global__ __launch_bounds__(256) void transpose_cast_kernel(const float* __restrict__ W,
                                                             unsigned short* __restrict__ Wt,
                                                             int n) {
  __shared__ float t[32][33];
  int bx = blockIdx.x * 32, by = blockIdx.y * 32;
  int x = threadIdx.x, y0 = threadIdx.y;
#pragma unroll
  for (int yy = 0; yy < 32; yy += 8)
    t[y0 + yy][x] = W[(long)(by + y0 + yy) * n + bx + x];
  __syncthreads();
#pragma unroll
  for (int yy = 0; yy < 32; yy += 8)
    Wt[(long)(bx + y0 + yy) * n + by + x] = f2bf(t[x][y0 + yy]);
}

// ---------------- pack mask (0/1 f32) into bit words, layout [B][S/64 kt][S q] ----------------
__global__ __launch_bounds__(256) void pack_mask_kernel(const float* __restrict__ mask,
                                                        unsigned long long* __restrict__ bits,
                                                        int nwords) {
  int lane = threadIdx.x & 63;
  int wpb = blockDim.x >> 6;
  int w = blockIdx.x * wpb + (threadIdx.x >> 6);
  int stride = gridDim.x * wpb;
  for (; w < nwords; w += stride) {
    float v = mask[(long)w * 64 + lane];
    unsigned long long b = __ballot(v > 0.5f);
    if (lane == 0) {
      int bb = w >> 16, q = (w >> 5) & 2047, kt64 = w & 31;
      bits[((long)bb << 16) | (kt64 << 11) | q] = b;
    }
  }
}

// ---------------- GEMM: C[M,N] = A[M,K] * Bt[N,K]^T + bias, bf16 MFMA ----------------
// MODE 0: bf16 out [M,N], val=(acc+bias)*scale
// MODE 1: bf16 out as per-head transposed V with key-permuted columns:
//         Vt[(b*16+h)*64+d][perm(s)], perm within each 32-block: p = gg*8 + b4*4 + r
//         for s&31 = b4*16 + gg*4 + r  (so attn's in-register P^T lines up as B-fragment)
// MODE 2: f32 out [M,N]
template <int MODE>
__global__ __launch_bounds__(256) void gemm_bt_kernel(const unsigned short* __restrict__ A,
                                                      const unsigned short* __restrict__ Bt,
                                                      const float* __restrict__ bias,
                                                      void* __restrict__ out,
                                                      int Mdim, int Ndim, int Kdim, float scale) {
  __shared__ unsigned short As[128 * 32];
  __shared__ unsigned short Bs[128 * 32];
  const int tid = threadIdx.x;
  const int lane = tid & 63;
  const int w = tid >> 6;
  const int g = lane >> 4;
  const int l15 = lane & 15;
  const int bm = blockIdx.x * 128;
  const int bn = blockIdx.y * 128;
  const int wr = w >> 1, wc = w & 1;

  f32x4 zero = {0.f, 0.f, 0.f, 0.f};
  f32x4 acc[4][4];
#pragma unroll
  for (int i = 0; i < 4; ++i)
#pragma unroll
    for (int j = 0; j < 4; ++j) acc[i][j] = zero;

  const int srow = lane >> 2;        // 0..15 within 16-row chunk
  const int scol = (lane & 3) * 8;   // bf16 col offset, 8 elems = 16B

  for (int k0 = 0; k0 < Kdim; k0 += 32) {
#pragma unroll
    for (int i = 0; i < 2; ++i) {
      int q = w * 2 + i;             // 1KB chunk index, rows [q*16, q*16+16)
      int row = q * 16 + srow;
      async_copy16(&A[(long)(bm + row) * Kdim + k0 + scol], &As[q * 512]);
      async_copy16(&Bt[(long)(bn + row) * Kdim + k0 + scol], &Bs[q * 512]);
    }
    __syncthreads();
    short8v a[4], b[4];
#pragma unroll
    for (int i = 0; i < 4; ++i)
      a[i] = *reinterpret_cast<const short8v*>(&As[(wr * 64 + i * 16 + l15) * 32 + g * 8]);
#pragma unroll
    for (int j = 0; j < 4; ++j)
      b[j] = *reinterpret_cast<const short8v*>(&Bs[(wc * 64 + j * 16 + l15) * 32 + g * 8]);
#pragma unroll
    for (int i = 0; i < 4; ++i)
#pragma unroll
      for (int j = 0; j < 4; ++j)
        acc[i][j] = __builtin_amdgcn_mfma_f32_16x16x32_bf16(a[i], b[j], acc[i][j], 0, 0, 0);
    __syncthreads();
  }

#pragma unroll
  for (int jj = 0; jj < 4; ++jj) {
    int n = bn + wc * 64 + jj * 16 + l15;
    float bs = bias[n];
#pragma unroll
    for (int i = 0; i < 4; ++i) {
      int m0 = bm + wr * 64 + i * 16 + g * 4;  // rows m0..m0+3 (reg r)
      if (MODE == 0) {
        unsigned short* o = (unsigned short*)out;
#pragma unroll
        for (int r = 0; r < 4; ++r)
          o[(long)(m0 + r) * Ndim + n] = f2bf((acc[i][jj][r] + bs) * scale);
      } else if (MODE == 1) {
        int b2 = m0 >> 11, s0 = m0 & 2047;
        // key permutation within 32-block (see comment above); (s0&3)==0 so 4 elems contiguous
        int s0p = (s0 & ~31) | (((s0 >> 2) & 3) << 3) | (((s0 >> 4) & 1) << 2);
        int h2 = n >> 6, d2 = n & 63;
        unsigned short* o = (unsigned short*)out;
        ushort4 v;
        v.x = f2bf(acc[i][jj][0] + bs);
        v.y = f2bf(acc[i][jj][1] + bs);
        v.z = f2bf(acc[i][jj][2] + bs);
        v.w = f2bf(acc[i][jj][3] + bs);
        *reinterpret_cast<ushort4*>(&o[((long)((b2 * 16 + h2) * 64 + d2) << 11) + s0p]) = v;
      } else {
        float* o = (float*)out;
#pragma unroll
        for (int r = 0; r < 4; ++r)
          o[(long)(m0 + r) * Ndim + n] = acc[i][jj][r] + bs;
      }
    }
  }
}

// ---------------- fused flash attention (v3: in-register P^T, exp2 domain) ----------------
// grid (S/128, B*H), 4 waves; wave w owns q rows qt*128 + w*32 .. +31 (2 q-fragments).
// K tile [64 keys][64 d] and permuted-V^T tile [64 d][64 keys'] staged in LDS, XOR-swizzled.
// Transposed logits Lt = mfma(K_frag, Q_frag): acc col = q = lane&15, row = key.
// The C/D rows each lane owns (keys g2*16+g*4+r) ARE a valid B-fragment under the
// key permutation baked into Vt -> P^T never leaves registers.
__global__ __launch_bounds__(256, 3) void attn_kernel(const unsigned short* __restrict__ Q,   // [B,S,D] pre-scaled log2e/8
                                                      const unsigned short* __restrict__ Kb,  // [B,S,D]
                                                      const unsigned short* __restrict__ Vt,  // [B*H,64,S] key-permuted
                                                      const unsigned long long* __restrict__ mbits, // [B][32][2048]
                                                      unsigned short* __restrict__ attn) {    // [B,S,D]
  __shared__ unsigned short Ks[64 * 64];       // swizzled, rows = key
  __shared__ unsigned short Vs[64 * 64];       // swizzled, rows = d
  const int lane = threadIdx.x & 63;
  const int w = threadIdx.x >> 6;
  const int g = lane >> 4;
  const int l15 = lane & 15;
  const int qt = blockIdx.x;
  const int bh = blockIdx.y;
  const int b = bh >> 4, h = bh & 15;
  const int q0 = qt * 128 + w * 32 + l15;  // qf=0 row; qf=1 row = q0+16

  // Q fragments double as MFMA B-operand: col n=q=lane&15, k=d=g*8+j (+32)
  const unsigned short* qp = Q + ((long)b * S_ + q0) * D_ + h * HD_ + g * 8;
  short8v qfr[2][2];
  qfr[0][0] = *reinterpret_cast<const short8v*>(qp);
  qfr[0][1] = *reinterpret_cast<const short8v*>(qp + 32);
  qfr[1][0] = *reinterpret_cast<const short8v*>(qp + 16 * D_);
  qfr[1][1] = *reinterpret_cast<const short8v*>(qp + 16 * D_ + 32);

  // staging: LDS chunk c holds global chunk c ^ (row&7)  (inverse-swizzled source)
  const int srow = lane >> 3;
  const int schunk = ((lane & 7) ^ (lane >> 3)) * 8;  // in elements
  const unsigned short* kstage = Kb + (long)b * S_ * D_ + h * HD_;
  const unsigned short* vstage = Vt + (long)bh * HD_ * S_;

  f32x4 zero = {0.f, 0.f, 0.f, 0.f};
  f32x4 oacc[2][4];
#pragma unroll
  for (int qf = 0; qf < 2; ++qf)
#pragma unroll
    for (int d = 0; d < 4; ++d) oacc[qf][d] = zero;
  float m_run[2] = {-1e30f, -1e30f}, l_run[2] = {0.f, 0.f};

  const unsigned long long* mbase = mbits + ((long)b << 16);
  const int swz = l15 & 7;

  for (int kt = 0; kt < S_; kt += 64) {
    // mask words for this tile (load early; latency hides under staging+QK^T)
    unsigned long long mw0 = mbase[((kt >> 6) << 11) + q0];
    unsigned long long mw1 = mbase[((kt >> 6) << 11) + q0 + 16];
    // ---- stage K/V tile (each wave issues 2+2 wave-loads of 1KB) ----
#pragma unroll
    for (int i = 0; i < 2; ++i) {
      int blk8 = w * 2 + i;
      async_copy16(&kstage[(long)(kt + blk8 * 8 + srow) * D_ + schunk], &Ks[blk8 * 512]);
      async_copy16(&vstage[(long)(blk8 * 8 + srow) * S_ + kt + schunk], &Vs[blk8 * 512]);
    }
    __syncthreads();

    // ---- QK^T (transposed), K frags shared across both q-fragments ----
    f32x4 lt[2][4];
#pragma unroll
    for (int g2 = 0; g2 < 4; ++g2) {
      const unsigned short* kr = &Ks[(g2 * 16 + l15) * 64];
      short8v kf0 = *reinterpret_cast<const short8v*>(&kr[(g ^ swz) * 8]);
      short8v kf1 = *reinterpret_cast<const short8v*>(&kr[((g + 4) ^ swz) * 8]);
#pragma unroll
      for (int qf = 0; qf < 2; ++qf) {
        f32x4 c = zero;
        c = __builtin_amdgcn_mfma_f32_16x16x32_bf16(kf0, qfr[qf][0], c, 0, 0, 0);
        c = __builtin_amdgcn_mfma_f32_16x16x32_bf16(kf1, qfr[qf][1], c, 0, 0, 0);
        lt[qf][g2] = c;
      }
    }

    // ---- online softmax per q-fragment, fully in-register ----
    short8v pfr[2][2];
#pragma unroll
    for (int qf = 0; qf < 2; ++qf) {
      unsigned long long mw = qf ? mw1 : mw0;
      float tmax = -1e30f;
#pragma unroll
      for (int g2 = 0; g2 < 4; ++g2)
#pragma unroll
        for (int r = 0; r < 4; ++r) {
          int krel = g2 * 16 + g * 4 + r;  // Lt row = key
          float v = ((mw >> krel) & 1ull) ? -1e30f : lt[qf][g2][r];
          lt[qf][g2][r] = v;
          tmax = fmaxf(tmax, v);
        }
      tmax = fmaxf(tmax, __shfl_xor(tmax, 16));
      tmax = fmaxf(tmax, __shfl_xor(tmax, 32));
      float m_new = fmaxf(m_run[qf], tmax);
      float alpha = __builtin_amdgcn_exp2f(m_run[qf] - m_new);
      float p[4][4];
      float tsum = 0.f;
#pragma unroll
      for (int g2 = 0; g2 < 4; ++g2)
#pragma unroll
        for (int r = 0; r < 4; ++r) {
          p[g2][r] = __builtin_amdgcn_exp2f(lt[qf][g2][r] - m_new);
          tsum += p[g2][r];
        }
      tsum += __shfl_xor(tsum, 16);
      tsum += __shfl_xor(tsum, 32);
      l_run[qf] = l_run[qf] * alpha + tsum;
      m_run[qf] = m_new;
#pragma unroll
      for (int d = 0; d < 4; ++d) oacc[qf][d] *= alpha;
      // pack P^T B-fragment in-register: pfr[s][j] = p[2s + (j>>2)][j&3]
#pragma unroll
      for (int s = 0; s < 2; ++s) {
        union { unsigned u[4]; short8v v; } pu;
        pu.u[0] = cvt_pk_bf16(p[2 * s][0], p[2 * s][1]);
        pu.u[1] = cvt_pk_bf16(p[2 * s][2], p[2 * s][3]);
        pu.u[2] = cvt_pk_bf16(p[2 * s + 1][0], p[2 * s + 1][1]);
        pu.u[3] = cvt_pk_bf16(p[2 * s + 1][2], p[2 * s + 1][3]);
        pfr[qf][s] = pu.v;
      }
    }

    // ---- PV: O^T += V^T * P^T, V frags shared across both q-fragments ----
#pragma unroll
    for (int d0 = 0; d0 < 4; ++d0) {
      const unsigned short* vr = &Vs[(d0 * 16 + l15) * 64];
#pragma unroll
      for (int s = 0; s < 2; ++s) {
        short8v vf = *reinterpret_cast<const short8v*>(&vr[((s * 4 + g) ^ swz) * 8]);
#pragma unroll
        for (int qf = 0; qf < 2; ++qf)
          oacc[qf][d0] = __builtin_amdgcn_mfma_f32_16x16x32_bf16(vf, pfr[qf][s], oacc[qf][d0], 0, 0, 0);
      }
    }
    __syncthreads();
  }

#pragma unroll
  for (int qf = 0; qf < 2; ++qf) {
    float inv = 1.f / l_run[qf];
    int q = q0 + qf * 16;
#pragma unroll
    for (int d0 = 0; d0 < 4; ++d0) {
      ushort4 o;
      o.x = f2bf(oacc[qf][d0][0] * inv);
      o.y = f2bf(oacc[qf][d0][1] * inv);
      o.z = f2bf(oacc[qf][d0][2] * inv);
      o.w = f2bf(oacc[qf][d0][3] * inv);
      *reinterpret_cast<ushort4*>(&attn[((long)b * S_ + q) * D_ + h * HD_ + d0 * 16 + g * 4]) = o;
    }
  }
}

// ---------------- launch ----------------
extern "C" void kernel_launch(void* const* d_in, const int* in_sizes, int n_in,
                              void* d_out, int out_size, void* d_ws, size_t ws_size,
                              hipStream_t stream) {
  const float* query = (const float*)d_in[0];
  const float* key   = (const float*)d_in[1];
  const float* value = (const float*)d_in[2];
  const float* mask  = (const float*)d_in[3];
  const float* Wq = (const float*)d_in[4];
  const float* bq = (const float*)d_in[5];
  const float* Wk = (const float*)d_in[6];
  const float* bk = (const float*)d_in[7];
  const float* Wv = (const float*)d_in[8];
  const float* bv = (const float*)d_in[9];
  const float* Wo = (const float*)d_in[10];
  const float* bo = (const float*)d_in[11];

  char* ws = (char*)d_ws;
  // layout (bytes): XQ 0..16M, XK 16..32M, XV 32..48M, weights 48..56M,
  // QB 56..72M, KB 72..88M, VT 88..104M. attn reuses XQ, mask bits reuse XK.
  unsigned short* XQ  = (unsigned short*)(ws);
  unsigned short* XK  = (unsigned short*)(ws + (16ull << 20));
  unsigned short* XV  = (unsigned short*)(ws + (32ull << 20));
  unsigned short* WQT = (unsigned short*)(ws + (48ull << 20));
  unsigned short* WKT = (unsigned short*)(ws + (50ull << 20));
  unsigned short* WVT = (unsigned short*)(ws + (52ull << 20));
  unsigned short* WOT = (unsigned short*)(ws + (54ull << 20));
  unsigned short* QB  = (unsigned short*)(ws + (56ull << 20));
  unsigned short* KB  = (unsigned short*)(ws + (72ull << 20));
  unsigned short* VT  = (unsigned short*)(ws + (88ull << 20));
  unsigned long long* MBITS = (unsigned long long*)(ws + (16ull << 20));
  unsigned short* ATTN = XQ;

  const int n4 = M_ * D_ / 4;
  cast_bf16_kernel<<<2048, 256, 0, stream>>>(query, XQ, n4);
  cast_bf16_kernel<<<2048, 256, 0, stream>>>(key,   XK, n4);
  cast_bf16_kernel<<<2048, 256, 0, stream>>>(value, XV, n4);

  dim3 tg(D_ / 32, D_ / 32), tb(32, 8);
  transpose_cast_kernel<<<tg, tb, 0, stream>>>(Wq, WQT, D_);
  transpose_cast_kernel<<<tg, tb, 0, stream>>>(Wk, WKT, D_);
  transpose_cast_kernel<<<tg, tb, 0, stream>>>(Wv, WVT, D_);
  transpose_cast_kernel<<<tg, tb, 0, stream>>>(Wo, WOT, D_);

  dim3 gg(M_ / 128, D_ / 128);
  // Q prescale: 1/sqrt(HD) * log2(e) so softmax runs in exp2 domain
  gemm_bt_kernel<0><<<gg, 256, 0, stream>>>(XQ, WQT, bq, QB, M_, D_, D_, 0.18033688011112042f);
  gemm_bt_kernel<0><<<gg, 256, 0, stream>>>(XK, WKT, bk, KB, M_, D_, D_, 1.f);
  gemm_bt_kernel<1><<<gg, 256, 0, stream>>>(XV, WVT, bv, VT, M_, D_, D_, 1.f);

  pack_mask_kernel<<<2048, 256, 0, stream>>>(mask, MBITS, B_ * S_ * S_ / 64);

  dim3 ag(S_ / 128, B_ * H_);
  attn_kernel<<<ag, 256, 0, stream>>>(QB, KB, VT, MBITS, ATTN);

  gemm_bt_kernel<2><<<gg, 256, 0, stream>>>(ATTN, WOT, bo, d_out, M_, D_, D_, 1.f);
}